// Round 3
// baseline (330.114 us; speedup 1.0000x reference)
//
#include <hip/hip_runtime.h>
#include <hip/hip_bf16.h>

// out[m, i] = sum_{j<=i} X[m, j] * W[i, j] + b[i]
// => C = X @ tril(W)^T + b  :  M=65536, N=512, K=512, fp32 in/out.
// R3: LDS-free, barrier-free MFMA GEMM.
//   - prep kernel: ws <- bf16(tril(W)) once (512 KB, L2-resident).
//   - main kernel: A-frags loaded directly global->reg (fp32->bf16 cvt),
//     B-frags as single 16B loads from ws. No __shared__, no __syncthreads.
//   - frag layout (validated R1/R2): lane holds [row=l&15][k=(l>>4)*8+j].

#define TK 512
#define BM 128
#define BN 128

typedef __attribute__((ext_vector_type(4))) float f32x4;
typedef __attribute__((ext_vector_type(4))) __bf16 bf16x4;
typedef __attribute__((ext_vector_type(8))) __bf16 bf16x8;

// ---- prep: ws[i][j] = (j<=i) ? bf16(W[i][j]) : 0 ----
__global__ __launch_bounds__(256)
void prep_w_kernel(const float* __restrict__ W, __bf16* __restrict__ Wb) {
    const int tid = blockIdx.x * 256 + threadIdx.x;   // 65536 threads
    const int i  = tid >> 7;          // row 0..511
    const int j0 = (tid & 127) * 4;   // col group
    f32x4 v = *reinterpret_cast<const f32x4*>(W + (size_t)i * TK + j0);
    bf16x4 o;
    #pragma unroll
    for (int e = 0; e < 4; ++e)
        o[e] = (j0 + e <= i) ? (__bf16)v[e] : (__bf16)0.f;
    *reinterpret_cast<bf16x4*>(Wb + (size_t)i * TK + j0) = o;
}

// ---- main GEMM ----
__global__ __launch_bounds__(256, 3)
void triu_gemm_kernel(const float* __restrict__ X, const __bf16* __restrict__ Wb,
                      const float* __restrict__ bias, float* __restrict__ out) {
    const int bm = blockIdx.x * BM;
    const int n0 = blockIdx.y * BN;
    const int kmax = n0 + BN;                 // triangular skip

    const int t    = threadIdx.x;
    const int wave = t >> 6;
    const int lane = t & 63;
    const int wr   = wave >> 1;               // 2x2 wave grid, 64x64 per wave
    const int wc   = wave & 1;
    const int l15  = lane & 15;
    const int l4   = lane >> 4;               // k-subchunk 0..3

    // per-frag base pointers (lane-resolved); inner loop adds kk
    const float*  xb[4];
    const __bf16* wb[4];
    #pragma unroll
    for (int m = 0; m < 4; ++m)
        xb[m] = X + (size_t)(bm + wr * 64 + m * 16 + l15) * TK + l4 * 8;
    #pragma unroll
    for (int n = 0; n < 4; ++n)
        wb[n] = Wb + (size_t)(n0 + wc * 64 + n * 16 + l15) * TK + l4 * 8;

    f32x4 acc[4][4];
    #pragma unroll
    for (int m = 0; m < 4; ++m)
        #pragma unroll
        for (int n = 0; n < 4; ++n)
            acc[m][n] = (f32x4){0.f, 0.f, 0.f, 0.f};

    #pragma unroll 2
    for (int kk = 0; kk < kmax; kk += 32) {
        bf16x8 a[4], b[4];
        #pragma unroll
        for (int m = 0; m < 4; ++m) {
            f32x4 v0 = *reinterpret_cast<const f32x4*>(xb[m] + kk);
            f32x4 v1 = *reinterpret_cast<const f32x4*>(xb[m] + kk + 4);
            #pragma unroll
            for (int e = 0; e < 4; ++e) a[m][e]     = (__bf16)v0[e];
            #pragma unroll
            for (int e = 0; e < 4; ++e) a[m][4 + e] = (__bf16)v1[e];
        }
        #pragma unroll
        for (int n = 0; n < 4; ++n)
            b[n] = *reinterpret_cast<const bf16x8*>(wb[n] + kk);

        #pragma unroll
        for (int m = 0; m < 4; ++m)
            #pragma unroll
            for (int n = 0; n < 4; ++n)
                acc[m][n] = __builtin_amdgcn_mfma_f32_16x16x32_bf16(
                    a[m], b[n], acc[m][n], 0, 0, 0);
    }

    // epilogue: C/D layout col = lane&15, row = (lane>>4)*4 + reg
    #pragma unroll
    for (int n = 0; n < 4; ++n) {
        const int col = n0 + wc * 64 + n * 16 + l15;
        const float bv = bias[col];
        #pragma unroll
        for (int m = 0; m < 4; ++m) {
            const int row0 = bm + wr * 64 + m * 16 + l4 * 4;
            #pragma unroll
            for (int j = 0; j < 4; ++j)
                out[(size_t)(row0 + j) * TK + col] = acc[m][n][j] + bv;
        }
    }
}

extern "C" void kernel_launch(void* const* d_in, const int* in_sizes, int n_in,
                              void* d_out, int out_size, void* d_ws, size_t ws_size,
                              hipStream_t stream) {
    const float* X = (const float*)d_in[0];
    const float* W = (const float*)d_in[1];
    const float* b = (const float*)d_in[2];
    float* out = (float*)d_out;
    __bf16* Wb = (__bf16*)d_ws;               // 512*512*2 = 512 KB

    prep_w_kernel<<<256, 256, 0, stream>>>(W, Wb);

    const int M = in_sizes[0] / TK;           // 65536
    dim3 grid(M / BM, TK / BN);               // (512, 4)
    triu_gemm_kernel<<<grid, 256, 0, stream>>>(X, Wb, b, out);
}

// Round 5
// 259.319 us; speedup vs baseline: 1.2730x; 1.2730x over previous
//
#include <hip/hip_runtime.h>
#include <hip/hip_bf16.h>

// out[m, i] = sum_{j<=i} X[m, j] * W[i, j] + b[i]
// => C = X @ tril(W)^T + b  :  M=65536, N=512, K=512, fp32 in/out.
// R4 (resubmit after broker timeout): m97-structure GEMM. prep kernel bakes
// bf16(tril(W)) into ws; main loop stages A (fp32) and B (bf16) via
// global_load_lds width=16 (12 DMA issues, no staging VALU). LDS dest linear
// (gload_lds requirement); XOR swizzle via pre-swizzled GLOBAL source address
// + un-XOR at read (rule 21). 48 KB LDS -> 3 blocks/CU; TLP hides the
// vmcnt(0)+barrier drain.

#define TK 512
#define BM 128
#define BN 128
#define BK 64

typedef __attribute__((ext_vector_type(4))) float f32x4;
typedef __attribute__((ext_vector_type(4))) __bf16 bf16x4;
typedef __attribute__((ext_vector_type(8))) __bf16 bf16x8;

__device__ __forceinline__ void gload_lds16(const void* g, void* l) {
    __builtin_amdgcn_global_load_lds(
        (const __attribute__((address_space(1))) unsigned int*)g,
        (__attribute__((address_space(3))) unsigned int*)l, 16, 0, 0);
}

// ---- prep: Wb[i][j] = (j<=i) ? bf16(W[i][j]) : 0 ----
__global__ __launch_bounds__(256)
void prep_w_kernel(const float* __restrict__ W, __bf16* __restrict__ Wb) {
    const int tid = blockIdx.x * 256 + threadIdx.x;   // 65536 threads
    const int i  = tid >> 7;
    const int j0 = (tid & 127) * 4;
    f32x4 v = *reinterpret_cast<const f32x4*>(W + (size_t)i * TK + j0);
    bf16x4 o;
    #pragma unroll
    for (int e = 0; e < 4; ++e)
        o[e] = (j0 + e <= i) ? (__bf16)v[e] : (__bf16)0.f;
    *reinterpret_cast<bf16x4*>(Wb + (size_t)i * TK + j0) = o;
}

// ---- main GEMM ----
__global__ __launch_bounds__(256, 3)
void triu_gemm_kernel(const float* __restrict__ X, const __bf16* __restrict__ Wb,
                      const float* __restrict__ bias, float* __restrict__ out) {
    // A: fp32 [128][64] = 32 KB; B: bf16 [128][64] = 16 KB. Linear layout;
    // 16B chunk within a row holds global chunk (c ^ (row&7)).
    __shared__ float  As[BM][BK];
    __shared__ __bf16 Bs[BN][BK];

    const int bm = blockIdx.x * BM;
    const int n0 = blockIdx.y * BN;
    const int kmax = n0 + BN;                 // triangular skip

    const int t    = threadIdx.x;
    const int wave = t >> 6;
    const int lane = t & 63;
    const int wr   = wave >> 1;
    const int wc   = wave & 1;
    const int l15  = lane & 15;
    const int l4   = lane >> 4;

    // staging address precompute (per-thread, loop adds k0)
    // A: 2048 16B-chunks, 8 issues/thread. p = i*256+t; row=p>>4, c=p&15.
    const float* srcA[8]; float* dstA[8];
    #pragma unroll
    for (int i = 0; i < 8; ++i) {
        const int p = i * 256 + t, row = p >> 4, c = p & 15;
        srcA[i] = X + (size_t)(bm + row) * TK + ((c ^ (row & 7)) << 2);
        dstA[i] = &As[0][0] + p * 4;
    }
    // B: 1024 16B-chunks, 4 issues/thread. row=p>>3, c=p&7.
    const __bf16* srcB[4]; __bf16* dstB[4];
    #pragma unroll
    for (int i = 0; i < 4; ++i) {
        const int p = i * 256 + t, row = p >> 3, c = p & 7;
        srcB[i] = Wb + (size_t)(n0 + row) * TK + ((c ^ (row & 7)) << 3);
        dstB[i] = &Bs[0][0] + p * 8;
    }

    f32x4 acc[4][4];
    #pragma unroll
    for (int m = 0; m < 4; ++m)
        #pragma unroll
        for (int n = 0; n < 4; ++n)
            acc[m][n] = (f32x4){0.f, 0.f, 0.f, 0.f};

    for (int k0 = 0; k0 < kmax; k0 += BK) {
        // ---- stage tile k0: 12 DMA issues, zero VALU staging ----
        #pragma unroll
        for (int i = 0; i < 8; ++i) gload_lds16(srcA[i] + k0, dstA[i]);
        #pragma unroll
        for (int i = 0; i < 4; ++i) gload_lds16(srcB[i] + k0, dstB[i]);
        __syncthreads();   // compiler drains vmcnt(0) before barrier

        // ---- compute: 2 k-substeps of 32 ----
        #pragma unroll
        for (int ks = 0; ks < 2; ++ks) {
            bf16x8 a[4], b[4];
            #pragma unroll
            for (int m = 0; m < 4; ++m) {
                const int row = wr * 64 + m * 16 + l15;
                const int c0 = (ks * 8 + l4 * 2)     ^ (row & 7);
                const int c1 = (ks * 8 + l4 * 2 + 1) ^ (row & 7);
                f32x4 v0 = *reinterpret_cast<const f32x4*>(&As[row][c0 * 4]);
                f32x4 v1 = *reinterpret_cast<const f32x4*>(&As[row][c1 * 4]);
                #pragma unroll
                for (int e = 0; e < 4; ++e) a[m][e]     = (__bf16)v0[e];
                #pragma unroll
                for (int e = 0; e < 4; ++e) a[m][4 + e] = (__bf16)v1[e];
            }
            #pragma unroll
            for (int n = 0; n < 4; ++n) {
                const int row = wc * 64 + n * 16 + l15;
                const int c = (ks * 4 + l4) ^ (row & 7);
                b[n] = *reinterpret_cast<const bf16x8*>(&Bs[row][c * 8]);
            }
            #pragma unroll
            for (int m = 0; m < 4; ++m)
                #pragma unroll
                for (int n = 0; n < 4; ++n)
                    acc[m][n] = __builtin_amdgcn_mfma_f32_16x16x32_bf16(
                        a[m], b[n], acc[m][n], 0, 0, 0);
        }
        __syncthreads();   // all reads done before next stage overwrites
    }

    // ---- epilogue: C/D layout col = lane&15, row = (lane>>4)*4 + reg ----
    #pragma unroll
    for (int n = 0; n < 4; ++n) {
        const int col = n0 + wc * 64 + n * 16 + l15;
        const float bv = bias[col];
        #pragma unroll
        for (int m = 0; m < 4; ++m) {
            const int row0 = bm + wr * 64 + m * 16 + l4 * 4;
            #pragma unroll
            for (int j = 0; j < 4; ++j)
                out[(size_t)(row0 + j) * TK + col] = acc[m][n][j] + bv;
        }
    }
}

extern "C" void kernel_launch(void* const* d_in, const int* in_sizes, int n_in,
                              void* d_out, int out_size, void* d_ws, size_t ws_size,
                              hipStream_t stream) {
    const float* X = (const float*)d_in[0];
    const float* W = (const float*)d_in[1];
    const float* b = (const float*)d_in[2];
    float* out = (float*)d_out;
    __bf16* Wb = (__bf16*)d_ws;               // 512*512*2 = 512 KB

    prep_w_kernel<<<256, 256, 0, stream>>>(W, Wb);

    const int M = in_sizes[0] / TK;           // 65536
    dim3 grid(M / BM, TK / BN);               // (512, 4)
    triu_gemm_kernel<<<grid, 256, 0, stream>>>(X, Wb, b, out);
}